// Round 1
// baseline (1387.676 us; speedup 1.0000x reference)
//
#include <hip/hip_runtime.h>

#define N_NODES   100000
#define N_EDGES   3200000
#define N_GRAPHS  1000
#define FEAT      512
#define EMB       7
#define N_CLASSES 10

// ---------------- init: deg=1 (self loop), agg=0, counts=0, flag=0 ----------
__global__ void k_init(float* __restrict__ deg, float* __restrict__ agg,
                       int* __restrict__ counts, int* __restrict__ flag) {
    int i = blockIdx.x * blockDim.x + threadIdx.x;
    if (i < N_NODES * EMB) agg[i] = 0.0f;
    if (i < N_NODES)       deg[i] = 1.0f;   // self-loop
    if (i < N_GRAPHS)      counts[i] = 0;
    if (i == 0)            *flag = 0;
}

// ---------------- detect int32 vs int64 storage of index inputs -------------
// int64 values < 2^31 -> odd 32-bit words are all zero. Random int32 indices
// (0..99999) make "first 2048 odd words all zero" impossible.
__global__ void k_detect(const int* __restrict__ w, int* __restrict__ flag) {
    int i = threadIdx.x;
    int any = 0;
    for (int k = i; k < 2048; k += 256)
        if (w[2 * k + 1] != 0) any = 1;
    if (any) atomicOr(flag, 1);   // 1 => int32 storage, 0 => int64 storage
}

__device__ __forceinline__ int load_idx(const void* p, long long i, int is32) {
    if (is32) return ((const int*)p)[i];
    return (int)((const long long*)p)[i];
}

// ---------------- per-graph node counts (batch_index sorted) ----------------
__global__ void k_count(const void* __restrict__ batch, const int* __restrict__ flag,
                        int* __restrict__ counts) {
    int i = blockIdx.x * blockDim.x + threadIdx.x;
    if (i >= N_NODES) return;
    int is32 = *flag;
    int g = load_idx(batch, i, is32);
    atomicAdd(&counts[g], 1);
}

// ---------------- degree: deg[dst] += 1 per edge ----------------------------
__global__ void k_deg(const void* __restrict__ eidx, const int* __restrict__ flag,
                      float* __restrict__ deg) {
    int e = blockIdx.x * blockDim.x + threadIdx.x;
    if (e >= N_EDGES) return;
    int is32 = *flag;
    int d = load_idx(eidx, (long long)N_EDGES + e, is32);
    atomicAdd(&deg[d], 1.0f);
}

// ---------------- dinv = rsqrt(deg) (deg >= 1 always) -----------------------
__global__ void k_dinv(float* __restrict__ deg) {
    int i = blockIdx.x * blockDim.x + threadIdx.x;
    if (i < N_NODES) deg[i] = rsqrtf(deg[i]);
}

// ---------------- h = x @ W_in  [100000,512]@[512,7] ------------------------
// thread-per-node; x read as float4 (coalesced across the wave's 64 rows,
// 128B-line reuse via L1); W indices are wave-uniform -> scalar loads.
__global__ void k_matmul(const float* __restrict__ x, const float* __restrict__ W,
                         float* __restrict__ h) {
    int n = blockIdx.x * blockDim.x + threadIdx.x;
    if (n >= N_NODES) return;
    const float4* xr = (const float4*)(x + (size_t)n * FEAT);
    float acc[EMB];
#pragma unroll
    for (int j = 0; j < EMB; ++j) acc[j] = 0.0f;
#pragma unroll 4
    for (int k4 = 0; k4 < FEAT / 4; ++k4) {
        float4 v = xr[k4];
        const float* w = W + k4 * 4 * EMB;
#pragma unroll
        for (int j = 0; j < EMB; ++j) {
            float a = acc[j];
            a = fmaf(v.x, w[0 * EMB + j], a);
            a = fmaf(v.y, w[1 * EMB + j], a);
            a = fmaf(v.z, w[2 * EMB + j], a);
            a = fmaf(v.w, w[3 * EMB + j], a);
            acc[j] = a;
        }
    }
    float* hn = h + (size_t)n * EMB;
#pragma unroll
    for (int j = 0; j < EMB; ++j) hn[j] = acc[j];
}

// ---------------- exclusive scan of counts -> offs[0..N_GRAPHS] -------------
__global__ void k_scan(const int* __restrict__ counts, int* __restrict__ offs) {
    __shared__ int s[1024];
    int i = threadIdx.x;
    int v = (i < N_GRAPHS) ? counts[i] : 0;
    s[i] = v;
    __syncthreads();
    for (int off = 1; off < 1024; off <<= 1) {
        int t = (i >= off) ? s[i - off] : 0;
        __syncthreads();
        s[i] += t;
        __syncthreads();
    }
    if (i == 0) offs[0] = 0;
    if (i < N_GRAPHS) offs[i + 1] = s[i];
}

// ---------------- edge aggregation: agg[d] += h[s] * dinv[s]*dinv[d] --------
__global__ void k_edges(const void* __restrict__ eidx, const int* __restrict__ flag,
                        const float* __restrict__ h, const float* __restrict__ dinv,
                        float* __restrict__ agg) {
    int e = blockIdx.x * blockDim.x + threadIdx.x;
    if (e >= N_EDGES) return;
    int is32 = *flag;
    int s = load_idx(eidx, e, is32);
    int d = load_idx(eidx, (long long)N_EDGES + e, is32);
    float nrm = dinv[s] * dinv[d];
    const float* hs = h + (size_t)s * EMB;
    float* ad = agg + (size_t)d * EMB;
#pragma unroll
    for (int j = 0; j < EMB; ++j) atomicAdd(ad + j, hs[j] * nrm);
}

// ---------------- per-graph pool + logits + softmax -------------------------
// block g reduces out_j(n) = relu(agg + h*dinv^2 + b_in) over its node range.
__global__ void k_pool(const float* __restrict__ h, const float* __restrict__ agg,
                       const float* __restrict__ dinv, const float* __restrict__ b_in,
                       const int* __restrict__ offs, const float* __restrict__ W_out,
                       const float* __restrict__ b_out, float* __restrict__ out) {
    int g = blockIdx.x;
    int n0 = offs[g], n1 = offs[g + 1];
    float acc[EMB];
#pragma unroll
    for (int j = 0; j < EMB; ++j) acc[j] = 0.0f;
    for (int n = n0 + (int)threadIdx.x; n < n1; n += (int)blockDim.x) {
        float di = dinv[n];
        float sl = di * di;
#pragma unroll
        for (int j = 0; j < EMB; ++j) {
            float o = agg[(size_t)n * EMB + j] + h[(size_t)n * EMB + j] * sl + b_in[j];
            acc[j] += fmaxf(o, 0.0f);
        }
    }
    // wave reduce (width 64)
#pragma unroll
    for (int j = 0; j < EMB; ++j) {
        float v = acc[j];
        for (int o = 32; o > 0; o >>= 1) v += __shfl_down(v, o);
        acc[j] = v;
    }
    __shared__ float sred[4][EMB];
    int wave = threadIdx.x >> 6, lane = threadIdx.x & 63;
    if (lane == 0) {
#pragma unroll
        for (int j = 0; j < EMB; ++j) sred[wave][j] = acc[j];
    }
    __syncthreads();
    if (threadIdx.x == 0) {
        float sums[EMB];
#pragma unroll
        for (int j = 0; j < EMB; ++j)
            sums[j] = sred[0][j] + sred[1][j] + sred[2][j] + sred[3][j];
        float cnt = (float)(n1 - n0);
        float inv = 1.0f / fmaxf(cnt, 1.0f);
        float logit[N_CLASSES];
        float mx = -1e30f;
#pragma unroll
        for (int c = 0; c < N_CLASSES; ++c) {
            float l = b_out[c];
#pragma unroll
            for (int j = 0; j < EMB; ++j)
                l = fmaf(sums[j] * inv, W_out[j * N_CLASSES + c], l);
            logit[c] = l;
            mx = fmaxf(mx, l);
        }
        float se = 0.0f;
#pragma unroll
        for (int c = 0; c < N_CLASSES; ++c) {
            logit[c] = expf(logit[c] - mx);
            se += logit[c];
        }
        float is = 1.0f / se;
#pragma unroll
        for (int c = 0; c < N_CLASSES; ++c)
            out[(size_t)g * N_CLASSES + c] = logit[c] * is;
    }
}

extern "C" void kernel_launch(void* const* d_in, const int* in_sizes, int n_in,
                              void* d_out, int out_size, void* d_ws, size_t ws_size,
                              hipStream_t stream) {
    const float* x     = (const float*)d_in[0];
    const void*  eidx  = d_in[1];
    const void*  batch = d_in[2];
    const float* W_in  = (const float*)d_in[3];
    const float* b_in  = (const float*)d_in[4];
    // d_in[5], d_in[6] = W_conv1, b_conv1 — dead code in reference, unused.
    const float* W_out = (const float*)d_in[7];
    const float* b_out = (const float*)d_in[8];
    float* out = (float*)d_out;

    float* ws     = (float*)d_ws;
    float* deg    = ws;                          // N_NODES (becomes dinv)
    float* h      = deg + N_NODES;               // N_NODES*EMB
    float* agg    = h + (size_t)N_NODES * EMB;   // N_NODES*EMB
    int*   counts = (int*)(agg + (size_t)N_NODES * EMB);  // N_GRAPHS
    int*   offs   = counts + N_GRAPHS;           // N_GRAPHS+1
    int*   flag   = offs + N_GRAPHS + 1;         // 1

    const int B = 256;
    k_init<<<(N_NODES * EMB + B - 1) / B, B, 0, stream>>>(deg, agg, counts, flag);
    k_detect<<<1, B, 0, stream>>>((const int*)eidx, flag);
    k_count<<<(N_NODES + B - 1) / B, B, 0, stream>>>(batch, flag, counts);
    k_deg<<<(N_EDGES + B - 1) / B, B, 0, stream>>>(eidx, flag, deg);
    k_matmul<<<(N_NODES + B - 1) / B, B, 0, stream>>>(x, W_in, h);
    k_dinv<<<(N_NODES + B - 1) / B, B, 0, stream>>>(deg);
    k_scan<<<1, 1024, 0, stream>>>(counts, offs);
    k_edges<<<(N_EDGES + B - 1) / B, B, 0, stream>>>(eidx, flag, h, deg, agg);
    k_pool<<<N_GRAPHS, B, 0, stream>>>(h, agg, deg, b_in, offs, W_out, b_out, out);
}

// Round 2
// 293.177 us; speedup vs baseline: 4.7332x; 4.7332x over previous
//
#include <hip/hip_runtime.h>

#define N_NODES   100000
#define N_EDGES   3200000
#define N_GRAPHS  1000
#define FEAT      512
#define EMB       7
#define HP        8      // padded per-node feature stride (float4-friendly)
#define N_CLASSES 10
#define SCAN_B    1024
#define NB_SCAN   98     // ceil(100000/1024)

__device__ __forceinline__ int load_idx(const void* p, long long i, int is32) {
    if (is32) return ((const int*)p)[i];
    return (int)((const long long*)p)[i];
}

// ---------------- init: cnt=0, flag=0 ---------------------------------------
__global__ void k_init(int* __restrict__ cnt, int* __restrict__ flag) {
    int i = blockIdx.x * blockDim.x + threadIdx.x;
    if (i < N_NODES) cnt[i] = 0;
    if (i == 0) *flag = 0;
}

// ---------------- detect int32 vs int64 storage of index inputs -------------
__global__ void k_detect(const int* __restrict__ w, int* __restrict__ flag) {
    int i = threadIdx.x;
    int any = 0;
    for (int k = i; k < 2048; k += 256)
        if (w[2 * k + 1] != 0) any = 1;
    if (any) atomicOr(flag, 1);   // 1 => int32 storage, 0 => int64 storage
}

// ---------------- count + per-edge rank (the only global-atomic pass) -------
__global__ void k_rank(const void* __restrict__ eidx, const int* __restrict__ flag,
                       int* __restrict__ cnt, int* __restrict__ rank) {
    int e = blockIdx.x * blockDim.x + threadIdx.x;
    if (e >= N_EDGES) return;
    int is32 = *flag;
    int d = load_idx(eidx, (long long)N_EDGES + e, is32);
    rank[e] = atomicAdd(&cnt[d], 1);
}

// ---------------- dinv = rsqrt(deg), deg = cnt + 1 (self loop) --------------
__global__ void k_dinv(const int* __restrict__ cnt, float* __restrict__ dinv) {
    int i = blockIdx.x * blockDim.x + threadIdx.x;
    if (i < N_NODES) dinv[i] = rsqrtf((float)cnt[i] + 1.0f);
}

// ---------------- hs = (x @ W_in) * dinv[n]   [100000,512]@[512,7] ----------
__global__ void k_matmul(const float* __restrict__ x, const float* __restrict__ W,
                         const float* __restrict__ dinv, float* __restrict__ hs) {
    int n = blockIdx.x * blockDim.x + threadIdx.x;
    if (n >= N_NODES) return;
    const float4* xr = (const float4*)(x + (size_t)n * FEAT);
    float acc[EMB];
#pragma unroll
    for (int j = 0; j < EMB; ++j) acc[j] = 0.0f;
#pragma unroll 4
    for (int k4 = 0; k4 < FEAT / 4; ++k4) {
        float4 v = xr[k4];
        const float* w = W + k4 * 4 * EMB;
#pragma unroll
        for (int j = 0; j < EMB; ++j) {
            float a = acc[j];
            a = fmaf(v.x, w[0 * EMB + j], a);
            a = fmaf(v.y, w[1 * EMB + j], a);
            a = fmaf(v.z, w[2 * EMB + j], a);
            a = fmaf(v.w, w[3 * EMB + j], a);
            acc[j] = a;
        }
    }
    float di = dinv[n];
    float4* o = (float4*)(hs + (size_t)n * HP);
    o[0] = make_float4(acc[0] * di, acc[1] * di, acc[2] * di, acc[3] * di);
    o[1] = make_float4(acc[4] * di, acc[5] * di, acc[6] * di, 0.0f);
}

// ---------------- hierarchical exclusive scan of cnt -> offs ----------------
__global__ void k_scan1(const int* __restrict__ cnt, int* __restrict__ bsum) {
    __shared__ int sw[16];
    int b = blockIdx.x;
    int i = b * SCAN_B + threadIdx.x;
    int v = (i < N_NODES) ? cnt[i] : 0;
    for (int o = 32; o > 0; o >>= 1) v += __shfl_down(v, o);
    int wave = threadIdx.x >> 6, lane = threadIdx.x & 63;
    if (lane == 0) sw[wave] = v;
    __syncthreads();
    if (threadIdx.x == 0) {
        int s = 0;
#pragma unroll
        for (int k = 0; k < 16; ++k) s += sw[k];
        bsum[b] = s;
    }
}

__global__ void k_scan2(const int* __restrict__ bsum, int* __restrict__ bbase) {
    __shared__ int s[128];
    int i = threadIdx.x;
    int v = (i < NB_SCAN) ? bsum[i] : 0;
    s[i] = v;
    __syncthreads();
    for (int off = 1; off < 128; off <<= 1) {
        int t = (i >= off) ? s[i - off] : 0;
        __syncthreads();
        s[i] += t;
        __syncthreads();
    }
    if (i < NB_SCAN) bbase[i] = s[i] - v;   // exclusive
}

__global__ void k_scan3(const int* __restrict__ cnt, const int* __restrict__ bbase,
                        int* __restrict__ offs) {
    __shared__ int s[SCAN_B];
    int b = blockIdx.x;
    int i = b * SCAN_B + threadIdx.x;
    int v = (i < N_NODES) ? cnt[i] : 0;
    s[threadIdx.x] = v;
    __syncthreads();
    for (int off = 1; off < SCAN_B; off <<= 1) {
        int t = (threadIdx.x >= off) ? s[threadIdx.x - off] : 0;
        __syncthreads();
        s[threadIdx.x] += t;
        __syncthreads();
    }
    if (i < N_NODES) offs[i] = bbase[b] + s[threadIdx.x] - v;  // exclusive
}

// ---------------- scatter edges into CSR (no atomics) -----------------------
__global__ void k_scatter(const void* __restrict__ eidx, const int* __restrict__ flag,
                          const int* __restrict__ rank, const int* __restrict__ offs,
                          int* __restrict__ csr) {
    int e = blockIdx.x * blockDim.x + threadIdx.x;
    if (e >= N_EDGES) return;
    int is32 = *flag;
    int s = load_idx(eidx, e, is32);
    int d = load_idx(eidx, (long long)N_EDGES + e, is32);
    csr[offs[d] + rank[e]] = s;
}

// ---------------- gather: out[n] = relu(dinv[n]*(hs[n]+sum hs[src]) + b) ----
// 4 lanes per node; butterfly combine; float2 write per lane.
__global__ void k_gather(const int* __restrict__ csr, const int* __restrict__ offs,
                         const int* __restrict__ cnt, const float* __restrict__ hs,
                         const float* __restrict__ dinv, const float* __restrict__ b_in,
                         float* __restrict__ outn) {
    int t = blockIdx.x * blockDim.x + threadIdx.x;
    int n = t >> 2, q = t & 3;
    if (n >= N_NODES) return;
    const float4* h4 = (const float4*)hs;
    float acc[EMB];
#pragma unroll
    for (int j = 0; j < EMB; ++j) acc[j] = 0.0f;
    int o = offs[n], c = cnt[n];
    for (int k = q; k < c; k += 4) {
        int s = csr[o + k];
        float4 a = h4[(size_t)s * 2];
        float4 b = h4[(size_t)s * 2 + 1];
        acc[0] += a.x; acc[1] += a.y; acc[2] += a.z; acc[3] += a.w;
        acc[4] += b.x; acc[5] += b.y; acc[6] += b.z;
    }
    if (q == 0) {  // self-loop term: hs[n]
        float4 a = h4[(size_t)n * 2];
        float4 b = h4[(size_t)n * 2 + 1];
        acc[0] += a.x; acc[1] += a.y; acc[2] += a.z; acc[3] += a.w;
        acc[4] += b.x; acc[5] += b.y; acc[6] += b.z;
    }
#pragma unroll
    for (int j = 0; j < EMB; ++j) {
        acc[j] += __shfl_xor(acc[j], 1);
        acc[j] += __shfl_xor(acc[j], 2);
    }
    float di = dinv[n];
    int j0 = 2 * q;
    float v0 = fmaxf(fmaf(di, acc[j0], b_in[j0]), 0.0f);           // j0 in {0,2,4,6}
    float v1 = (j0 + 1 < EMB) ? fmaxf(fmaf(di, acc[j0 + 1], b_in[j0 + 1]), 0.0f) : 0.0f;
    ((float2*)(outn + (size_t)n * HP))[q] = make_float2(v0, v1);
}

// ---------------- graph offsets via binary search (batch sorted) ------------
__global__ void k_boffs(const void* __restrict__ batch, const int* __restrict__ flag,
                        int* __restrict__ goffs) {
    int g = blockIdx.x * blockDim.x + threadIdx.x;
    if (g > N_GRAPHS) return;
    int is32 = *flag;
    int lo = 0, hi = N_NODES;
    while (lo < hi) {
        int mid = (lo + hi) >> 1;
        int v = load_idx(batch, mid, is32);
        if (v < g) lo = mid + 1; else hi = mid;
    }
    goffs[g] = lo;   // first node with batch >= g; goffs[N_GRAPHS] = N_NODES
}

// ---------------- per-graph mean pool + logits + softmax --------------------
__global__ void k_pool(const float* __restrict__ outn, const int* __restrict__ goffs,
                       const float* __restrict__ W_out, const float* __restrict__ b_out,
                       float* __restrict__ out) {
    int g = blockIdx.x;
    int n0 = goffs[g], n1 = goffs[g + 1];
    float acc[EMB];
#pragma unroll
    for (int j = 0; j < EMB; ++j) acc[j] = 0.0f;
    for (int n = n0 + (int)threadIdx.x; n < n1; n += (int)blockDim.x) {
        const float4* o4 = (const float4*)(outn + (size_t)n * HP);
        float4 a = o4[0], b = o4[1];
        acc[0] += a.x; acc[1] += a.y; acc[2] += a.z; acc[3] += a.w;
        acc[4] += b.x; acc[5] += b.y; acc[6] += b.z;
    }
#pragma unroll
    for (int j = 0; j < EMB; ++j) {
        float v = acc[j];
        for (int o = 32; o > 0; o >>= 1) v += __shfl_down(v, o);
        acc[j] = v;
    }
    __shared__ float sred[4][EMB];
    int wave = threadIdx.x >> 6, lane = threadIdx.x & 63;
    if (lane == 0) {
#pragma unroll
        for (int j = 0; j < EMB; ++j) sred[wave][j] = acc[j];
    }
    __syncthreads();
    if (threadIdx.x == 0) {
        float sums[EMB];
#pragma unroll
        for (int j = 0; j < EMB; ++j)
            sums[j] = sred[0][j] + sred[1][j] + sred[2][j] + sred[3][j];
        float inv = 1.0f / fmaxf((float)(n1 - n0), 1.0f);
        float logit[N_CLASSES];
        float mx = -1e30f;
#pragma unroll
        for (int c = 0; c < N_CLASSES; ++c) {
            float l = b_out[c];
#pragma unroll
            for (int j = 0; j < EMB; ++j)
                l = fmaf(sums[j] * inv, W_out[j * N_CLASSES + c], l);
            logit[c] = l;
            mx = fmaxf(mx, l);
        }
        float se = 0.0f;
#pragma unroll
        for (int c = 0; c < N_CLASSES; ++c) {
            logit[c] = expf(logit[c] - mx);
            se += logit[c];
        }
        float is = 1.0f / se;
#pragma unroll
        for (int c = 0; c < N_CLASSES; ++c)
            out[(size_t)g * N_CLASSES + c] = logit[c] * is;
    }
}

extern "C" void kernel_launch(void* const* d_in, const int* in_sizes, int n_in,
                              void* d_out, int out_size, void* d_ws, size_t ws_size,
                              hipStream_t stream) {
    const float* x     = (const float*)d_in[0];
    const void*  eidx  = d_in[1];
    const void*  batch = d_in[2];
    const float* W_in  = (const float*)d_in[3];
    const float* b_in  = (const float*)d_in[4];
    // d_in[5], d_in[6] = W_conv1, b_conv1 — dead code in reference.
    const float* W_out = (const float*)d_in[7];
    const float* b_out = (const float*)d_in[8];
    float* out = (float*)d_out;

    // ---- workspace layout (~33.5 MB) ----
    int*   cnt   = (int*)d_ws;                 // 100000
    int*   rank  = cnt + N_NODES;              // 3200000
    int*   offs  = rank + N_EDGES;             // 100000
    int*   csr   = offs + N_NODES;             // 3200000
    float* hs    = (float*)(csr + N_EDGES);    // 100000*8
    float* outn  = hs + (size_t)N_NODES * HP;  // 100000*8
    float* dinv  = outn + (size_t)N_NODES * HP;// 100000
    int*   goffs = (int*)(dinv + N_NODES);     // 1001
    int*   bsum  = goffs + N_GRAPHS + 1;       // 98
    int*   bbase = bsum + NB_SCAN;             // 98
    int*   flag  = bbase + NB_SCAN;            // 1

    const int B = 256;
    k_init   <<<(N_NODES + B - 1) / B, B, 0, stream>>>(cnt, flag);
    k_detect <<<1, B, 0, stream>>>((const int*)eidx, flag);
    k_rank   <<<(N_EDGES + B - 1) / B, B, 0, stream>>>(eidx, flag, cnt, rank);
    k_dinv   <<<(N_NODES + B - 1) / B, B, 0, stream>>>(cnt, dinv);
    k_matmul <<<(N_NODES + B - 1) / B, B, 0, stream>>>(x, W_in, dinv, hs);
    k_scan1  <<<NB_SCAN, SCAN_B, 0, stream>>>(cnt, bsum);
    k_scan2  <<<1, 128, 0, stream>>>(bsum, bbase);
    k_scan3  <<<NB_SCAN, SCAN_B, 0, stream>>>(cnt, bbase, offs);
    k_scatter<<<(N_EDGES + B - 1) / B, B, 0, stream>>>(eidx, flag, rank, offs, csr);
    k_gather <<<(4 * N_NODES + B - 1) / B, B, 0, stream>>>(csr, offs, cnt, hs, dinv, b_in, outn);
    k_boffs  <<<(N_GRAPHS + 1 + 511) / 512, 512, 0, stream>>>(batch, flag, goffs);
    k_pool   <<<N_GRAPHS, B, 0, stream>>>(outn, goffs, W_out, b_out, out);
}

// Round 4
// 190.438 us; speedup vs baseline: 7.2868x; 1.5395x over previous
//
#include <hip/hip_runtime.h>

#define N_NODES   100000
#define N_EDGES   3200000
#define N_GRAPHS  1000
#define FEAT      512
#define EMB       7
#define HP        8      // padded per-node feature stride
#define N_CLASSES 10

#define NBUCK     1563   // buckets of 64 nodes: bucket = dst >> 6
#define NB_A      512    // partition blocks
#define TILE_A    6250   // edges per partition block (512*6250 == 3.2M exactly)
#define SEGCAP    4096   // max staged edges per bucket (mean 2048, +45 sigma)

__device__ __forceinline__ int load_idx(const void* p, long long i, int is32) {
    if (is32) return ((const int*)p)[i];
    return (int)((const long long*)p)[i];
}

// ---- detect int32 vs int64 index storage (also zero-inits flag) ------------
__global__ void k_detect(const int* __restrict__ w, int* __restrict__ flag) {
    if (threadIdx.x == 0) *flag = 0;
    __syncthreads();
    int any = 0;
    for (int k = threadIdx.x; k < 2048; k += 256)
        if (w[2 * k + 1] != 0) any = 1;
    if (any) atomicOr(flag, 1);   // 1 => int32, 0 => int64
}

// ---- pass A: per-block bucket histogram (LDS atomics only) -----------------
__global__ void k_bhist(const void* __restrict__ eidx, const int* __restrict__ flag,
                        int* __restrict__ T) {
    __shared__ int bins[NBUCK];
    int b = blockIdx.x;
    for (int k = threadIdx.x; k < NBUCK; k += blockDim.x) bins[k] = 0;
    __syncthreads();
    int is32 = *flag;
    long long e0 = (long long)b * TILE_A;
    for (int i = threadIdx.x; i < TILE_A; i += blockDim.x) {
        int d = load_idx(eidx, (long long)N_EDGES + e0 + i, is32);
        atomicAdd(&bins[d >> 6], 1);
    }
    __syncthreads();
    for (int k = threadIdx.x; k < NBUCK; k += blockDim.x)
        T[b * NBUCK + k] = bins[k];
}

// ---- pass B1: bucket totals (column reduce of T) ---------------------------
__global__ void k_btot(const int* __restrict__ T, int* __restrict__ btot) {
    int k = blockIdx.x;
    int s = 0;
    for (int b = threadIdx.x; b < NB_A; b += blockDim.x)
        s += T[b * NBUCK + k];
    for (int o = 32; o > 0; o >>= 1) s += __shfl_down(s, o);
    __shared__ int sw[4];
    int wave = threadIdx.x >> 6, lane = threadIdx.x & 63;
    if (lane == 0) sw[wave] = s;
    __syncthreads();
    if (threadIdx.x == 0) btot[k] = sw[0] + sw[1] + sw[2] + sw[3];
}

// ---- pass B2: exclusive scan of bucket totals -> base ----------------------
__global__ void k_bscan(const int* __restrict__ btot, int* __restrict__ base) {
    __shared__ int s[1024];
    int t = threadIdx.x;
    int a0 = (2 * t     < NBUCK) ? btot[2 * t]     : 0;
    int a1 = (2 * t + 1 < NBUCK) ? btot[2 * t + 1] : 0;
    int pair = a0 + a1;
    s[t] = pair;
    __syncthreads();
    for (int off = 1; off < 1024; off <<= 1) {
        int v = (t >= off) ? s[t - off] : 0;
        __syncthreads();
        s[t] += v;
        __syncthreads();
    }
    int excl = s[t] - pair;
    if (2 * t     < NBUCK) base[2 * t]     = excl;
    if (2 * t + 1 < NBUCK) base[2 * t + 1] = excl + a0;
}

// ---- pass B3: per-bucket column scan of T (in place) + add base ------------
__global__ void k_bcol(int* __restrict__ T, const int* __restrict__ base) {
    __shared__ int s[NB_A];
    int k = blockIdx.x;
    int t = threadIdx.x;                  // 512 threads == NB_A
    int v = T[t * NBUCK + k];
    s[t] = v;
    __syncthreads();
    for (int off = 1; off < NB_A; off <<= 1) {
        int u = (t >= off) ? s[t - off] : 0;
        __syncthreads();
        s[t] += u;
        __syncthreads();
    }
    T[t * NBUCK + k] = base[k] + s[t] - v;  // exclusive start per (block,bucket)
}

// ---- pass C: scatter edges into bucket-grouped array (packed) --------------
__global__ void k_part(const void* __restrict__ eidx, const int* __restrict__ flag,
                       const int* __restrict__ T, int* __restrict__ gpk) {
    __shared__ int cur[NBUCK];
    int b = blockIdx.x;
    for (int k = threadIdx.x; k < NBUCK; k += blockDim.x) cur[k] = T[b * NBUCK + k];
    __syncthreads();
    int is32 = *flag;
    long long e0 = (long long)b * TILE_A;
    for (int i = threadIdx.x; i < TILE_A; i += blockDim.x) {
        int src = load_idx(eidx, e0 + i, is32);
        int d   = load_idx(eidx, (long long)N_EDGES + e0 + i, is32);
        int slot = atomicAdd(&cur[d >> 6], 1);
        gpk[slot] = src | ((d & 63) << 17);   // src < 2^17, dstlocal 6 bits
    }
}

// ---- pass D: per-bucket node-level regroup (in place) + offs/cnt/dinv ------
__global__ void k_group(int* __restrict__ gpk, const int* __restrict__ base,
                        const int* __restrict__ btot, int* __restrict__ offs,
                        int* __restrict__ cnt, float* __restrict__ dinv) {
    __shared__ int stage[SEGCAP];
    __shared__ int bin[64], loff[64], curs[64];
    int k = blockIdx.x;
    int s0 = base[k];
    int len = btot[k];
    if (len > SEGCAP) len = SEGCAP;   // unreachable statistically
    for (int i = threadIdx.x; i < len; i += blockDim.x) stage[i] = gpk[s0 + i];
    if (threadIdx.x < 64) { bin[threadIdx.x] = 0; curs[threadIdx.x] = 0; }
    __syncthreads();
    for (int i = threadIdx.x; i < len; i += blockDim.x)
        atomicAdd(&bin[(stage[i] >> 17) & 63], 1);
    __syncthreads();
    if (threadIdx.x < 64) {            // wave-0 inclusive scan of 64 bins
        int v = bin[threadIdx.x];
        int inc = v;
        for (int o = 1; o < 64; o <<= 1) {
            int u = __shfl_up(inc, o);
            if ((threadIdx.x & 63) >= o) inc += u;
        }
        loff[threadIdx.x] = inc - v;   // exclusive
    }
    __syncthreads();
    for (int i = threadIdx.x; i < len; i += blockDim.x) {
        int p = stage[i];
        int dl = (p >> 17) & 63;
        int r = atomicAdd(&curs[dl], 1);
        gpk[s0 + loff[dl] + r] = p & 0x1FFFF;   // src only: node-grouped CSR
    }
    int node = k * 64 + threadIdx.x;
    if (threadIdx.x < 64 && node < N_NODES) {
        int c = bin[threadIdx.x];
        offs[node] = s0 + loff[threadIdx.x];
        cnt[node]  = c;
        dinv[node] = rsqrtf((float)c + 1.0f);
    }
}

// ---- hs = (x @ W_in) * dinv[n]   [100000,512]@[512,7] ----------------------
__global__ void k_matmul(const float* __restrict__ x, const float* __restrict__ W,
                         const float* __restrict__ dinv, float* __restrict__ hs) {
    int n = blockIdx.x * blockDim.x + threadIdx.x;
    if (n >= N_NODES) return;
    const float4* xr = (const float4*)(x + (size_t)n * FEAT);
    float acc[EMB];
#pragma unroll
    for (int j = 0; j < EMB; ++j) acc[j] = 0.0f;
#pragma unroll 4
    for (int k4 = 0; k4 < FEAT / 4; ++k4) {
        float4 v = xr[k4];
        const float* w = W + k4 * 4 * EMB;
#pragma unroll
        for (int j = 0; j < EMB; ++j) {
            float a = acc[j];
            a = fmaf(v.x, w[0 * EMB + j], a);
            a = fmaf(v.y, w[1 * EMB + j], a);
            a = fmaf(v.z, w[2 * EMB + j], a);
            a = fmaf(v.w, w[3 * EMB + j], a);
            acc[j] = a;
        }
    }
    float di = dinv[n];
    float4* o = (float4*)(hs + (size_t)n * HP);
    o[0] = make_float4(acc[0] * di, acc[1] * di, acc[2] * di, acc[3] * di);
    o[1] = make_float4(acc[4] * di, acc[5] * di, acc[6] * di, 0.0f);
}

// ---- gather: out[n] = relu(dinv[n]*(hs[n]+sum hs[src]) + b) ----------------
__global__ void k_gather(const int* __restrict__ csr, const int* __restrict__ offs,
                         const int* __restrict__ cnt, const float* __restrict__ hs,
                         const float* __restrict__ dinv, const float* __restrict__ b_in,
                         float* __restrict__ outn) {
    int t = blockIdx.x * blockDim.x + threadIdx.x;
    int n = t >> 2, q = t & 3;
    if (n >= N_NODES) return;
    const float4* h4 = (const float4*)hs;
    float acc[EMB];
#pragma unroll
    for (int j = 0; j < EMB; ++j) acc[j] = 0.0f;
    int o = offs[n], c = cnt[n];
    for (int k = q; k < c; k += 4) {
        int s = csr[o + k];
        float4 a = h4[(size_t)s * 2];
        float4 b = h4[(size_t)s * 2 + 1];
        acc[0] += a.x; acc[1] += a.y; acc[2] += a.z; acc[3] += a.w;
        acc[4] += b.x; acc[5] += b.y; acc[6] += b.z;
    }
    if (q == 0) {  // self loop
        float4 a = h4[(size_t)n * 2];
        float4 b = h4[(size_t)n * 2 + 1];
        acc[0] += a.x; acc[1] += a.y; acc[2] += a.z; acc[3] += a.w;
        acc[4] += b.x; acc[5] += b.y; acc[6] += b.z;
    }
#pragma unroll
    for (int j = 0; j < EMB; ++j) {
        acc[j] += __shfl_xor(acc[j], 1);
        acc[j] += __shfl_xor(acc[j], 2);
    }
    float di = dinv[n];
    int j0 = 2 * q;
    float v0 = fmaxf(fmaf(di, acc[j0], b_in[j0]), 0.0f);
    float v1 = (j0 + 1 < EMB) ? fmaxf(fmaf(di, acc[j0 + 1], b_in[j0 + 1]), 0.0f) : 0.0f;
    ((float2*)(outn + (size_t)n * HP))[q] = make_float2(v0, v1);
}

// ---- graph offsets via binary search (batch sorted) ------------------------
__global__ void k_boffs(const void* __restrict__ batch, const int* __restrict__ flag,
                        int* __restrict__ goffs) {
    int g = blockIdx.x * blockDim.x + threadIdx.x;
    if (g > N_GRAPHS) return;
    int is32 = *flag;
    int lo = 0, hi = N_NODES;
    while (lo < hi) {
        int mid = (lo + hi) >> 1;
        int v = load_idx(batch, mid, is32);
        if (v < g) lo = mid + 1; else hi = mid;
    }
    goffs[g] = lo;
}

// ---- per-graph mean pool + logits + softmax --------------------------------
__global__ void k_pool(const float* __restrict__ outn, const int* __restrict__ goffs,
                       const float* __restrict__ W_out, const float* __restrict__ b_out,
                       float* __restrict__ out) {
    int g = blockIdx.x;
    int n0 = goffs[g], n1 = goffs[g + 1];
    float acc[EMB];
#pragma unroll
    for (int j = 0; j < EMB; ++j) acc[j] = 0.0f;
    for (int n = n0 + (int)threadIdx.x; n < n1; n += (int)blockDim.x) {
        const float4* o4 = (const float4*)(outn + (size_t)n * HP);
        float4 a = o4[0], b = o4[1];
        acc[0] += a.x; acc[1] += a.y; acc[2] += a.z; acc[3] += a.w;
        acc[4] += b.x; acc[5] += b.y; acc[6] += b.z;
    }
#pragma unroll
    for (int j = 0; j < EMB; ++j) {
        float v = acc[j];
        for (int o = 32; o > 0; o >>= 1) v += __shfl_down(v, o);
        acc[j] = v;
    }
    __shared__ float sred[4][EMB];
    int wave = threadIdx.x >> 6, lane = threadIdx.x & 63;
    if (lane == 0) {
#pragma unroll
        for (int j = 0; j < EMB; ++j) sred[wave][j] = acc[j];
    }
    __syncthreads();
    if (threadIdx.x == 0) {
        float sums[EMB];
#pragma unroll
        for (int j = 0; j < EMB; ++j)
            sums[j] = sred[0][j] + sred[1][j] + sred[2][j] + sred[3][j];
        float inv = 1.0f / fmaxf((float)(n1 - n0), 1.0f);
        float logit[N_CLASSES];
        float mx = -1e30f;
#pragma unroll
        for (int c = 0; c < N_CLASSES; ++c) {
            float l = b_out[c];
#pragma unroll
            for (int j = 0; j < EMB; ++j)
                l = fmaf(sums[j] * inv, W_out[j * N_CLASSES + c], l);
            logit[c] = l;
            mx = fmaxf(mx, l);
        }
        float se = 0.0f;
#pragma unroll
        for (int c = 0; c < N_CLASSES; ++c) {
            logit[c] = expf(logit[c] - mx);
            se += logit[c];
        }
        float is = 1.0f / se;
#pragma unroll
        for (int c = 0; c < N_CLASSES; ++c)
            out[(size_t)g * N_CLASSES + c] = logit[c] * is;
    }
}

extern "C" void kernel_launch(void* const* d_in, const int* in_sizes, int n_in,
                              void* d_out, int out_size, void* d_ws, size_t ws_size,
                              hipStream_t stream) {
    const float* x     = (const float*)d_in[0];
    const void*  eidx  = d_in[1];
    const void*  batch = d_in[2];
    const float* W_in  = (const float*)d_in[3];
    const float* b_in  = (const float*)d_in[4];
    // d_in[5], d_in[6] = W_conv1, b_conv1 — dead code in reference.
    const float* W_out = (const float*)d_in[7];
    const float* b_out = (const float*)d_in[8];
    float* out = (float*)d_out;

    // ---- workspace layout (~23.7 MB) ----
    int*   gpk   = (int*)d_ws;                   // N_EDGES (bucket-grouped, then CSR in place)
    int*   T     = gpk + N_EDGES;                // NB_A * NBUCK
    int*   btot  = T + NB_A * NBUCK;             // NBUCK
    int*   base  = btot + NBUCK;                 // NBUCK
    int*   offs  = base + NBUCK;                 // N_NODES
    int*   cnt   = offs + N_NODES;               // N_NODES
    float* dinv  = (float*)(cnt + N_NODES);      // N_NODES
    float* hs    = dinv + N_NODES;               // N_NODES*HP
    float* outn  = hs + (size_t)N_NODES * HP;    // N_NODES*HP
    int*   goffs = (int*)(outn + (size_t)N_NODES * HP);  // N_GRAPHS+1
    int*   flag  = goffs + N_GRAPHS + 1;         // 1

    const int B = 256;
    k_detect<<<1, B, 0, stream>>>((const int*)eidx, flag);
    k_bhist <<<NB_A, B, 0, stream>>>(eidx, flag, T);
    k_btot  <<<NBUCK, B, 0, stream>>>(T, btot);
    k_bscan <<<1, 1024, 0, stream>>>(btot, base);
    k_bcol  <<<NBUCK, NB_A, 0, stream>>>(T, base);
    k_part  <<<NB_A, B, 0, stream>>>(eidx, flag, T, gpk);
    k_group <<<NBUCK, B, 0, stream>>>(gpk, base, btot, offs, cnt, dinv);
    k_matmul<<<(N_NODES + B - 1) / B, B, 0, stream>>>(x, W_in, dinv, hs);
    k_gather<<<(4 * N_NODES + B - 1) / B, B, 0, stream>>>(gpk, offs, cnt, hs, dinv, b_in, outn);
    k_boffs <<<(N_GRAPHS + 1 + 511) / 512, 512, 0, stream>>>(batch, flag, goffs);
    k_pool  <<<N_GRAPHS, B, 0, stream>>>(outn, goffs, W_out, b_out, out);
}

// Round 5
// 180.568 us; speedup vs baseline: 7.6851x; 1.0547x over previous
//
#include <hip/hip_runtime.h>

#define N_NODES   100000
#define N_EDGES   3200000
#define N_GRAPHS  1000
#define FEAT      512
#define EMB       7
#define HP        8      // padded per-node feature stride
#define N_CLASSES 10

#define BSH       8      // 256 nodes per bucket
#define DMASK     255
#define NBUCK     391    // ceil(100000/256)
#define NB_A      512    // partition blocks
#define TILE_A    6250   // 512*6250 == 3.2M exactly
#define SEGCAP    9216   // mean 8192, +11 sigma

__device__ __forceinline__ int load_idx(const void* p, long long i, int is32) {
    if (is32) return ((const int*)p)[i];
    return (int)((const long long*)p)[i];
}

// ---- self-detect int32 vs int64 storage of edge_index ----------------------
// Samples odd 32-bit words of the first 2048 entries (in-bounds for both
// formats). int64 indices < 2^31 -> all zero; int32 -> random src values,
// nonzero w.h.p. (P[all 2048 zero] ~ 1e-5^2048).
__device__ int edge_is32(const void* p) {
    __shared__ int sflag;
    if (threadIdx.x == 0) sflag = 0;
    __syncthreads();
    const int* w = (const int*)p;
    int any = 0;
    for (int k = threadIdx.x; k < 2048; k += blockDim.x)
        if (w[2 * k + 1] != 0) any = 1;
    if (any) atomicOr(&sflag, 1);
    __syncthreads();
    return sflag;
}

// batch is sorted starting at graph 0, so early odd words are 0 for BOTH
// formats; sample entries 1024..2047 (graphs ~10-20 if int32 -> nonzero).
__device__ int batch_is32(const void* p) {
    __shared__ int sflag;
    if (threadIdx.x == 0) sflag = 0;
    __syncthreads();
    const int* w = (const int*)p;
    int any = 0;
    for (int k = 1024 + threadIdx.x; k < 2048; k += blockDim.x)
        if (w[2 * k + 1] != 0) any = 1;
    if (any) atomicOr(&sflag, 1);
    __syncthreads();
    return sflag;
}

// ---- pass A: per-block bucket histogram (LDS atomics only) -----------------
__global__ void k_bhist(const void* __restrict__ eidx, int* __restrict__ T) {
    __shared__ int bins[NBUCK];
    int is32 = edge_is32(eidx);
    int b = blockIdx.x;
    for (int k = threadIdx.x; k < NBUCK; k += blockDim.x) bins[k] = 0;
    __syncthreads();
    long long e0 = (long long)b * TILE_A;
    for (int i = threadIdx.x; i < TILE_A; i += blockDim.x) {
        int d = load_idx(eidx, (long long)N_EDGES + e0 + i, is32);
        atomicAdd(&bins[d >> BSH], 1);
    }
    __syncthreads();
    for (int k = threadIdx.x; k < NBUCK; k += blockDim.x)
        T[b * NBUCK + k] = bins[k];
}

// ---- pass B1: bucket totals (column reduce of T), 512 threads --------------
__global__ void k_btot(const int* __restrict__ T, int* __restrict__ btot) {
    __shared__ int sw[8];
    int k = blockIdx.x;
    int v = T[threadIdx.x * NBUCK + k];
    for (int o = 32; o > 0; o >>= 1) v += __shfl_down(v, o);
    if ((threadIdx.x & 63) == 0) sw[threadIdx.x >> 6] = v;
    __syncthreads();
    if (threadIdx.x == 0) {
        int s = 0;
#pragma unroll
        for (int w = 0; w < 8; ++w) s += sw[w];
        btot[k] = s;
    }
}

// ---- pass B2: per-bucket prefix base + column scan of T (fused) ------------
__global__ void k_bcol(int* __restrict__ T, const int* __restrict__ btot,
                       int* __restrict__ base) {
    __shared__ int s[NB_A];
    __shared__ int sw[8];
    __shared__ int bkv;
    int k = blockIdx.x, t = threadIdx.x;
    // base[k] = sum_{j<k} btot[j]  (k < 391 <= 512, one element per thread)
    int v = (t < k) ? btot[t] : 0;
    for (int o = 32; o > 0; o >>= 1) v += __shfl_down(v, o);
    if ((t & 63) == 0) sw[t >> 6] = v;
    __syncthreads();
    if (t == 0) {
        int a = 0;
#pragma unroll
        for (int w = 0; w < 8; ++w) a += sw[w];
        bkv = a;
        base[k] = a;
    }
    // column scan (exclusive) over the 512 partition blocks
    int c = T[t * NBUCK + k];
    s[t] = c;
    __syncthreads();
    for (int off = 1; off < NB_A; off <<= 1) {
        int u = (t >= off) ? s[t - off] : 0;
        __syncthreads();
        s[t] += u;
        __syncthreads();
    }
    T[t * NBUCK + k] = bkv + s[t] - c;   // global start per (block,bucket)
}

// ---- pass C: scatter edges into bucket-grouped array (packed) --------------
__global__ void k_part(const void* __restrict__ eidx, const int* __restrict__ T,
                       int* __restrict__ gpk) {
    __shared__ int cur[NBUCK];
    int is32 = edge_is32(eidx);
    int b = blockIdx.x;
    for (int k = threadIdx.x; k < NBUCK; k += blockDim.x) cur[k] = T[b * NBUCK + k];
    __syncthreads();
    long long e0 = (long long)b * TILE_A;
    for (int i = threadIdx.x; i < TILE_A; i += blockDim.x) {
        int src = load_idx(eidx, e0 + i, is32);
        int d   = load_idx(eidx, (long long)N_EDGES + e0 + i, is32);
        int slot = atomicAdd(&cur[d >> BSH], 1);
        gpk[slot] = src | ((d & DMASK) << 17);   // src < 2^17, dstlocal 8 bits
    }
}

// ---- pass D: per-bucket node-level regroup (in place) + offs/cnt/dinv ------
__global__ void k_group(int* __restrict__ gpk, const int* __restrict__ base,
                        const int* __restrict__ btot, int* __restrict__ offs,
                        int* __restrict__ cnt, float* __restrict__ dinv) {
    __shared__ int stage[SEGCAP];
    __shared__ int bin[256], loff[256], curs[256], sinc[256];
    int k = blockIdx.x, t = threadIdx.x;
    int s0 = base[k];
    int len = btot[k];
    if (len > SEGCAP) len = SEGCAP;   // statistically unreachable
    for (int i = t; i < len; i += blockDim.x) stage[i] = gpk[s0 + i];
    if (t < 256) { bin[t] = 0; curs[t] = 0; }
    __syncthreads();
    for (int i = t; i < len; i += blockDim.x)
        atomicAdd(&bin[(stage[i] >> 17) & DMASK], 1);
    __syncthreads();
    if (t < 256) {                    // 4-wave inclusive scan of 256 bins
        int v = bin[t];
        int inc = v;
        for (int o = 1; o < 64; o <<= 1) {
            int u = __shfl_up(inc, o);
            if ((t & 63) >= o) inc += u;
        }
        sinc[t] = inc;
    }
    __syncthreads();
    if (t < 256) {
        int w = t >> 6;
        int add = 0;
        if (w >= 1) add += sinc[63];
        if (w >= 2) add += sinc[127];
        if (w >= 3) add += sinc[191];
        loff[t] = sinc[t] - bin[t] + add;   // exclusive within bucket
    }
    __syncthreads();
    for (int i = t; i < len; i += blockDim.x) {
        int p = stage[i];
        int dl = (p >> 17) & DMASK;
        int r = atomicAdd(&curs[dl], 1);
        gpk[s0 + loff[dl] + r] = p & 0x1FFFF;   // node-grouped CSR (src only)
    }
    int node = (k << BSH) + t;
    if (t < 256 && node < N_NODES) {
        int c = bin[t];
        offs[node] = s0 + loff[t];
        cnt[node]  = c;
        dinv[node] = rsqrtf((float)c + 1.0f);
    }
}

// ---- hs = (x @ W_in) * dinv[n]   [100000,512]@[512,7] ----------------------
__global__ void k_matmul(const float* __restrict__ x, const float* __restrict__ W,
                         const float* __restrict__ dinv, float* __restrict__ hs) {
    int n = blockIdx.x * blockDim.x + threadIdx.x;
    if (n >= N_NODES) return;
    const float4* xr = (const float4*)(x + (size_t)n * FEAT);
    float acc[EMB];
#pragma unroll
    for (int j = 0; j < EMB; ++j) acc[j] = 0.0f;
#pragma unroll 4
    for (int k4 = 0; k4 < FEAT / 4; ++k4) {
        float4 v = xr[k4];
        const float* w = W + k4 * 4 * EMB;
#pragma unroll
        for (int j = 0; j < EMB; ++j) {
            float a = acc[j];
            a = fmaf(v.x, w[0 * EMB + j], a);
            a = fmaf(v.y, w[1 * EMB + j], a);
            a = fmaf(v.z, w[2 * EMB + j], a);
            a = fmaf(v.w, w[3 * EMB + j], a);
            acc[j] = a;
        }
    }
    float di = dinv[n];
    float4* o = (float4*)(hs + (size_t)n * HP);
    o[0] = make_float4(acc[0] * di, acc[1] * di, acc[2] * di, acc[3] * di);
    o[1] = make_float4(acc[4] * di, acc[5] * di, acc[6] * di, 0.0f);
}

// ---- gather: out[n] = relu(dinv[n]*(hs[n]+sum hs[src]) + b) ----------------
__global__ void k_gather(const int* __restrict__ csr, const int* __restrict__ offs,
                         const int* __restrict__ cnt, const float* __restrict__ hs,
                         const float* __restrict__ dinv, const float* __restrict__ b_in,
                         float* __restrict__ outn) {
    int t = blockIdx.x * blockDim.x + threadIdx.x;
    int n = t >> 2, q = t & 3;
    if (n >= N_NODES) return;
    const float4* h4 = (const float4*)hs;
    float acc[EMB];
#pragma unroll
    for (int j = 0; j < EMB; ++j) acc[j] = 0.0f;
    int o = offs[n], c = cnt[n];
    for (int k = q; k < c; k += 4) {
        int s = csr[o + k];
        float4 a = h4[(size_t)s * 2];
        float4 b = h4[(size_t)s * 2 + 1];
        acc[0] += a.x; acc[1] += a.y; acc[2] += a.z; acc[3] += a.w;
        acc[4] += b.x; acc[5] += b.y; acc[6] += b.z;
    }
    if (q == 0) {  // self loop
        float4 a = h4[(size_t)n * 2];
        float4 b = h4[(size_t)n * 2 + 1];
        acc[0] += a.x; acc[1] += a.y; acc[2] += a.z; acc[3] += a.w;
        acc[4] += b.x; acc[5] += b.y; acc[6] += b.z;
    }
#pragma unroll
    for (int j = 0; j < EMB; ++j) {
        acc[j] += __shfl_xor(acc[j], 1);
        acc[j] += __shfl_xor(acc[j], 2);
    }
    float di = dinv[n];
    int j0 = 2 * q;
    float v0 = fmaxf(fmaf(di, acc[j0], b_in[j0]), 0.0f);
    float v1 = (j0 + 1 < EMB) ? fmaxf(fmaf(di, acc[j0 + 1], b_in[j0 + 1]), 0.0f) : 0.0f;
    ((float2*)(outn + (size_t)n * HP))[q] = make_float2(v0, v1);
}

// ---- per-graph mean pool + logits + softmax (fused binary search) ----------
__global__ void k_pool(const float* __restrict__ outn, const void* __restrict__ batch,
                       const float* __restrict__ W_out, const float* __restrict__ b_out,
                       float* __restrict__ out) {
    int g = blockIdx.x;
    int is32 = batch_is32(batch);
    int n0, n1;
    {
        int lo = 0, hi = N_NODES;
        while (lo < hi) { int m = (lo + hi) >> 1; if (load_idx(batch, m, is32) < g) lo = m + 1; else hi = m; }
        n0 = lo;
        hi = N_NODES;
        while (lo < hi) { int m = (lo + hi) >> 1; if (load_idx(batch, m, is32) < g + 1) lo = m + 1; else hi = m; }
        n1 = lo;
    }
    float acc[EMB];
#pragma unroll
    for (int j = 0; j < EMB; ++j) acc[j] = 0.0f;
    for (int n = n0 + (int)threadIdx.x; n < n1; n += (int)blockDim.x) {
        const float4* o4 = (const float4*)(outn + (size_t)n * HP);
        float4 a = o4[0], b = o4[1];
        acc[0] += a.x; acc[1] += a.y; acc[2] += a.z; acc[3] += a.w;
        acc[4] += b.x; acc[5] += b.y; acc[6] += b.z;
    }
#pragma unroll
    for (int j = 0; j < EMB; ++j) {
        float v = acc[j];
        for (int o = 32; o > 0; o >>= 1) v += __shfl_down(v, o);
        acc[j] = v;
    }
    __shared__ float sred[4][EMB];
    int wave = threadIdx.x >> 6, lane = threadIdx.x & 63;
    if (lane == 0) {
#pragma unroll
        for (int j = 0; j < EMB; ++j) sred[wave][j] = acc[j];
    }
    __syncthreads();
    if (threadIdx.x == 0) {
        float sums[EMB];
#pragma unroll
        for (int j = 0; j < EMB; ++j)
            sums[j] = sred[0][j] + sred[1][j] + sred[2][j] + sred[3][j];
        float inv = 1.0f / fmaxf((float)(n1 - n0), 1.0f);
        float logit[N_CLASSES];
        float mx = -1e30f;
#pragma unroll
        for (int c = 0; c < N_CLASSES; ++c) {
            float l = b_out[c];
#pragma unroll
            for (int j = 0; j < EMB; ++j)
                l = fmaf(sums[j] * inv, W_out[j * N_CLASSES + c], l);
            logit[c] = l;
            mx = fmaxf(mx, l);
        }
        float se = 0.0f;
#pragma unroll
        for (int c = 0; c < N_CLASSES; ++c) {
            logit[c] = expf(logit[c] - mx);
            se += logit[c];
        }
        float is = 1.0f / se;
#pragma unroll
        for (int c = 0; c < N_CLASSES; ++c)
            out[(size_t)g * N_CLASSES + c] = logit[c] * is;
    }
}

extern "C" void kernel_launch(void* const* d_in, const int* in_sizes, int n_in,
                              void* d_out, int out_size, void* d_ws, size_t ws_size,
                              hipStream_t stream) {
    const float* x     = (const float*)d_in[0];
    const void*  eidx  = d_in[1];
    const void*  batch = d_in[2];
    const float* W_in  = (const float*)d_in[3];
    const float* b_in  = (const float*)d_in[4];
    // d_in[5], d_in[6] = W_conv1, b_conv1 — dead code in reference.
    const float* W_out = (const float*)d_in[7];
    const float* b_out = (const float*)d_in[8];
    float* out = (float*)d_out;

    // ---- workspace layout (~21 MB) ----
    int*   gpk   = (int*)d_ws;                   // N_EDGES
    int*   T     = gpk + N_EDGES;                // NB_A * NBUCK (800 KB)
    int*   btot  = T + NB_A * NBUCK;             // NBUCK
    int*   base  = btot + NBUCK;                 // NBUCK
    int*   offs  = base + NBUCK;                 // N_NODES
    int*   cnt   = offs + N_NODES;               // N_NODES
    float* dinv  = (float*)(cnt + N_NODES);      // N_NODES
    float* hs    = dinv + N_NODES;               // N_NODES*HP
    float* outn  = hs + (size_t)N_NODES * HP;    // N_NODES*HP

    const int B = 256;
    k_bhist <<<NB_A, B, 0, stream>>>(eidx, T);
    k_btot  <<<NBUCK, NB_A, 0, stream>>>(T, btot);
    k_bcol  <<<NBUCK, NB_A, 0, stream>>>(T, btot, base);
    k_part  <<<NB_A, B, 0, stream>>>(eidx, T, gpk);
    k_group <<<NBUCK, NB_A, 0, stream>>>(gpk, base, btot, offs, cnt, dinv);
    k_matmul<<<(N_NODES + B - 1) / B, B, 0, stream>>>(x, W_in, dinv, hs);
    k_gather<<<(4 * N_NODES + B - 1) / B, B, 0, stream>>>(gpk, offs, cnt, hs, dinv, b_in, outn);
    k_pool  <<<N_GRAPHS, B, 0, stream>>>(outn, batch, W_out, b_out, out);
}